// Round 4
// baseline (326.730 us; speedup 1.0000x reference)
//
#include <hip/hip_runtime.h>

#define NB 64
#define NPRED 25200
#define NCAND 2048
#define NSEL 1024
#define NDET 300
#define NBINS 8192
#define CONF_T 0.25f
#define IOU_T 0.45f
#define BASE_BITS 0x3E800000u   // bits of 0.25f

__device__ __forceinline__ float sigmoidf_(float x) {
    return 1.0f / (1.0f + expf(-x));
}

// ---------------------------------------------------------------- scores
// score = valid ? obj*sigmoid(max raw_cls) : 0   (monotonicity of sigmoid)
__global__ void k_score(const float* __restrict__ r0,
                        const float* __restrict__ r1,
                        const float* __restrict__ r2,
                        float* __restrict__ scores) {
    int tid = blockIdx.x * blockDim.x + threadIdx.x;
    if (tid >= NB * NPRED) return;
    int img = tid / NPRED;
    int n = tid - img * NPRED;
    const float* src;
    int local, cells;
    if (n < 19200)      { src = r0; local = n;         cells = 6400; }
    else if (n < 24000) { src = r1; local = n - 19200; cells = 1600; }
    else                { src = r2; local = n - 24000; cells = 400;  }
    long base = ((long)img * 3 * cells + local) * 20;
    const float4* p = (const float4*)(src + base + 4);   // raw[4..19], 16B aligned
    float4 v0 = p[0], v1 = p[1], v2 = p[2], v3 = p[3];
    float obj = sigmoidf_(v0.x);
    float m = v0.y;
    m = fmaxf(m, v0.z); m = fmaxf(m, v0.w);
    m = fmaxf(m, v1.x); m = fmaxf(m, v1.y); m = fmaxf(m, v1.z); m = fmaxf(m, v1.w);
    m = fmaxf(m, v2.x); m = fmaxf(m, v2.y); m = fmaxf(m, v2.z); m = fmaxf(m, v2.w);
    m = fmaxf(m, v3.x); m = fmaxf(m, v3.y); m = fmaxf(m, v3.z); m = fmaxf(m, v3.w);
    float best = obj * sigmoidf_(m);
    float sc = (obj > CONF_T && best > CONF_T) ? best : 0.0f;
    scores[tid] = sc;
}

// ---------------------------------------------------------------- top-k (fused select+sort)
// Per-image block. Scores live in registers (25/thread). Histogram over float
// bits of (0.25,1.0) -> threshold bin -> compact into LDS -> bitonic sort of
// 2048 packed keys (scoreBits<<32)|(~idx) == exact lax.top_k order.
__global__ __launch_bounds__(1024) void k_topk(const float* __restrict__ scores,
                                               float* __restrict__ sel_score,
                                               int* __restrict__ sel_idx) {
    __shared__ unsigned int hist[NBINS];
    __shared__ unsigned int bufA[1024];
    __shared__ unsigned int bufB[1024];
    __shared__ unsigned long long sbuf[NCAND];
    __shared__ unsigned int s_thr;
    __shared__ unsigned int s_cnt;
    int img = blockIdx.x;
    int t = threadIdx.x;
    for (int b = t; b < NBINS; b += 1024) hist[b] = 0;
    if (t == 0) { s_thr = 0; s_cnt = 0; }
    __syncthreads();
    const float* sc = scores + (long)img * NPRED;
    float v[25];
#pragma unroll
    for (int i = 0; i < 25; ++i) {
        int n = t + i * 1024;
        v[i] = (n < NPRED) ? sc[n] : 0.0f;
        if (v[i] > CONF_T) {
            unsigned bin = (__float_as_uint(v[i]) - BASE_BITS) >> 11;
            if (bin > NBINS - 1u) bin = NBINS - 1u;
            atomicAdd(&hist[bin], 1u);
        }
    }
    __syncthreads();
    unsigned h[8];
    unsigned cs = 0;
    for (int b = 0; b < 8; ++b) { h[b] = hist[t * 8 + b]; cs += h[b]; }
    bufA[t] = cs;
    __syncthreads();
    unsigned int* srcp = bufA;
    unsigned int* dstp = bufB;
    for (int ofs = 1; ofs < 1024; ofs <<= 1) {
        unsigned vv = srcp[t];
        if (t >= ofs) vv += srcp[t - ofs];
        dstp[t] = vv;
        __syncthreads();
        unsigned int* tmp = srcp; srcp = dstp; dstp = tmp;
    }
    unsigned total = srcp[1023];
    unsigned above = total - srcp[t];
    if (total >= NSEL) {
        unsigned c = above;
        for (int b = 7; b >= 0; --b) {
            unsigned ci = c + h[b];
            if (c < NSEL && ci >= NSEL) {
                s_thr = BASE_BITS + ((unsigned)(t * 8 + b) << 11);
            }
            c = ci;
        }
    }
    __syncthreads();
    unsigned thr = s_thr;
#pragma unroll
    for (int i = 0; i < 25; ++i) {
        int n = t + i * 1024;
        if (v[i] > CONF_T) {
            unsigned bits = __float_as_uint(v[i]);
            if (bits >= thr) {
                unsigned pos = atomicAdd(&s_cnt, 1u);
                if (pos < NCAND)
                    sbuf[pos] = ((unsigned long long)bits << 32) |
                                (unsigned long long)(0xFFFFFFFFu - (unsigned)n);
            }
        }
    }
    __syncthreads();
    for (unsigned pos = s_cnt + (unsigned)t; pos < NCAND; pos += 1024) sbuf[pos] = 0ull;
    __syncthreads();
    for (int k = 2; k <= NCAND; k <<= 1) {
        for (int j = k >> 1; j > 0; j >>= 1) {
            for (int e = t; e < NCAND; e += 1024) {
                int p = e ^ j;
                if (p > e) {
                    unsigned long long a = sbuf[e], b = sbuf[p];
                    bool up = ((e & k) == 0);
                    if ((a < b) == up) { sbuf[e] = b; sbuf[p] = a; }
                }
            }
            __syncthreads();
        }
    }
    unsigned long long key = sbuf[t];
    float scv = __uint_as_float((unsigned)(key >> 32));
    int idx = (int)(0xFFFFFFFFu - (unsigned)(key & 0xFFFFFFFFull));
    sel_score[img * NSEL + t] = scv;
    sel_idx[img * NSEL + t] = idx;
}

// ---------------------------------------------------------------- decode selected
__global__ void k_decode(const float* __restrict__ r0, const float* __restrict__ r1,
                         const float* __restrict__ r2, const float* __restrict__ strd,
                         const float* __restrict__ ag,
                         const float* __restrict__ sel_score,
                         const int* __restrict__ sel_idx,
                         float* __restrict__ sel_box, float* __restrict__ sel_cls) {
    int t = blockIdx.x * blockDim.x + threadIdx.x;
    if (t >= NB * NSEL) return;
    int img = t >> 10;
    float scv = sel_score[t];
    float4 bb = make_float4(0.f, 0.f, 0.f, 0.f);
    float cls = 0.0f;
    if (scv > CONF_T) {
        int n = sel_idx[t];
        const float* src;
        int a, y, x, cells, sidx, nxl;
        if (n < 19200) {
            sidx = 0; src = r0; cells = 6400; nxl = 80;
            int l = n;            a = l / 6400; int r = l - a * 6400; y = r / 80; x = r - y * 80;
        } else if (n < 24000) {
            sidx = 1; src = r1; cells = 1600; nxl = 40;
            int l = n - 19200;    a = l / 1600; int r = l - a * 1600; y = r / 40; x = r - y * 40;
        } else {
            sidx = 2; src = r2; cells = 400; nxl = 20;
            int l = n - 24000;    a = l / 400;  int r = l - a * 400;  y = r / 20; x = r - y * 20;
        }
        long base = (((long)img * 3 + a) * cells + (long)y * nxl + x) * 20;
        const float4* p = (const float4*)(src + base);
        float4 v0 = p[0];
        float st = strd[sidx];
        float aw = ag[(sidx * 3 + a) * 2 + 0];
        float ah = ag[(sidx * 3 + a) * 2 + 1];
        float cx = (sigmoidf_(v0.x) * 2.0f - 0.5f + (float)x) * st;
        float cy = (sigmoidf_(v0.y) * 2.0f - 0.5f + (float)y) * st;
        float tw = sigmoidf_(v0.z) * 2.0f;
        float th = sigmoidf_(v0.w) * 2.0f;
        float w = tw * tw * aw;
        float h = th * th * ah;
        bb.x = cx - w * 0.5f;
        bb.y = cy - h * 0.5f;
        bb.z = cx + w * 0.5f;
        bb.w = cy + h * 0.5f;
        float4 c0 = p[1], c1 = p[2], c2 = p[3], c3 = p[4];
        float vals[15] = { c0.y, c0.z, c0.w,
                           c1.x, c1.y, c1.z, c1.w,
                           c2.x, c2.y, c2.z, c2.w,
                           c3.x, c3.y, c3.z, c3.w };
        float bv = vals[0]; int bi = 0;
        for (int k = 1; k < 15; ++k) if (vals[k] > bv) { bv = vals[k]; bi = k; }
        cls = (float)bi;
    }
    ((float4*)sel_box)[t] = bb;
    sel_cls[t] = cls;
}

// ---------------------------------------------------------------- IoU mask (tiled)
// maskT[img][jt][i]: bit b set <=> j=jt*64+b > i and IoU > 0.45.
// One wave per 64x64 tile; lane = j; j-boxes in regs, i-boxes wave-uniform LDS.
__global__ __launch_bounds__(256) void k_mask(const float* __restrict__ sel_box,
                                              unsigned long long* __restrict__ maskT) {
    __shared__ float4 boxi[64];
    __shared__ float areai[64];
    int img = blockIdx.x >> 6;
    int rem = blockIdx.x & 63;
    int it = rem >> 2;          // 0..15
    int q  = rem & 3;           // 0..3
    int t = threadIdx.x;
    int wv = t >> 6;            // wave 0..3
    int lane = t & 63;
    const float4* bsrc = (const float4*)sel_box + (long)img * NSEL;
    if (t < 64) {
        float4 b = bsrc[it * 64 + t];
        boxi[t] = b;
        areai[t] = (b.z - b.x) * (b.w - b.y);
    }
    __syncthreads();
    int jt = q * 4 + wv;        // 0..15
    unsigned long long* dst =
        maskT + ((long)img * 16 + jt) * NSEL + it * 64 + lane;
    if (jt < it) { *dst = 0ull; return; }
    float4 bj = bsrc[jt * 64 + lane];
    float aj = (bj.z - bj.x) * (bj.w - bj.y);
    bool diag = (jt == it);
    unsigned long long myword = 0;
    for (int i = 0; i < 64; ++i) {
        float4 bi = boxi[i];
        float ai = areai[i];
        float iw = fminf(bi.z, bj.z) - fmaxf(bi.x, bj.x);
        float ih = fminf(bi.w, bj.w) - fmaxf(bi.y, bj.y);
        iw = fmaxf(iw, 0.0f);
        ih = fmaxf(ih, 0.0f);
        float inter = iw * ih;
        float iou = inter / (ai + aj - inter + 1e-7f);
        bool pred = (iou > IOU_T) && (!diag || lane > i);
        unsigned long long bal = __ballot(pred);
        if (lane == i) myword = bal;
    }
    *dst = myword;
}

// ---------------------------------------------------------------- sweep + output (fused)
// Wave 0: greedy NMS sweep, keep words (lanes 0..15, lo/hi split) with
// double-buffered 16-row register prefetch of maskT (lane w reads column w).
// Then all 16 waves emit the first 300 kept rows.
#define SWEEP_CH16(kc, CUR, NXT, HALF)                                    \
    {                                                                     \
        if ((kc) + 1 < 64) {                                              \
            _Pragma("unroll")                                             \
            for (int d = 0; d < 16; ++d)                                  \
                NXT[d] = ldv ? lp[((kc) + 1) * 16 + d] : 0ull;            \
        }                                                                 \
        int widx = (kc) >> 2;                                             \
        _Pragma("unroll")                                                 \
        for (int d = 0; d < 16; ++d) {                                    \
            unsigned cur = (unsigned)__builtin_amdgcn_readlane(           \
                (int)(HALF), widx);                                       \
            unsigned long long mm =                                       \
                (cur & (1u << ((((kc) & 1) << 4) + d))) ? CUR[d] : 0ull;  \
            kwlo &= ~(unsigned)mm;                                        \
            kwhi &= ~(unsigned)(mm >> 32);                                \
        }                                                                 \
    }

__global__ __launch_bounds__(1024) void k_sweepout(const float* __restrict__ sel_score,
                                                   const float* __restrict__ sel_box,
                                                   const float* __restrict__ sel_cls,
                                                   const unsigned long long* __restrict__ maskT,
                                                   float* __restrict__ out) {
    __shared__ unsigned long long keepL[16];
    __shared__ unsigned int wsum[16];
    int img = blockIdx.x, t = threadIdx.x;
    int lane = t & 63, wid = t >> 6;
    const float* sc = sel_score + img * NSEL;
    if (wid == 0) {
        unsigned long long kw = 0;
        for (int g = 0; g < 16; ++g) {
            unsigned long long bal = __ballot(sc[g * 64 + lane] > CONF_T);
            if (lane == g) kw = bal;
        }
        unsigned kwlo = (unsigned)kw;
        unsigned kwhi = (unsigned)(kw >> 32);
        bool ldv = lane < 16;
        const unsigned long long* lp =
            maskT + (long)img * 16 * NSEL + (long)(ldv ? lane : 0) * NSEL;
        unsigned long long bufA[16], bufB[16];
#pragma unroll
        for (int d = 0; d < 16; ++d) bufA[d] = ldv ? lp[d] : 0ull;
        for (int kc = 0; kc < 64; kc += 4) {
            SWEEP_CH16(kc,     bufA, bufB, kwlo);
            SWEEP_CH16(kc + 1, bufB, bufA, kwlo);
            SWEEP_CH16(kc + 2, bufA, bufB, kwhi);
            SWEEP_CH16(kc + 3, bufB, bufA, kwhi);
        }
        if (lane < 16)
            keepL[lane] =
                ((unsigned long long)kwhi << 32) | (unsigned long long)kwlo;
    }
    __syncthreads();
    float* o = out + (long)img * NDET * 6;
    for (int e = t; e < NDET * 6; e += 1024) o[e] = 0.0f;
    bool kept = (keepL[wid] >> lane) & 1ull;
    unsigned long long bal = __ballot(kept);
    int lrank = __popcll(bal & ((1ull << lane) - 1ull));
    if (lane == 0) wsum[wid] = (unsigned)__popcll(bal);
    __syncthreads();
    int off = 0;
    for (int ww = 0; ww < wid; ++ww) off += (int)wsum[ww];
    int rank = off + lrank;
    if (kept && rank < NDET) {
        float4 b = ((const float4*)sel_box)[img * NSEL + t];
        float s = sc[t];
        float c = sel_cls[img * NSEL + t];
        float* row = o + rank * 6;
        row[0] = b.x; row[1] = b.y; row[2] = b.z; row[3] = b.w;
        row[4] = s;   row[5] = c;
    }
}

// ---------------------------------------------------------------- launch
extern "C" void kernel_launch(void* const* d_in, const int* in_sizes, int n_in,
                              void* d_out, int out_size, void* d_ws, size_t ws_size,
                              hipStream_t stream) {
    const float* r0   = (const float*)d_in[0];
    const float* r1   = (const float*)d_in[1];
    const float* r2   = (const float*)d_in[2];
    const float* strd = (const float*)d_in[3];
    const float* ag   = (const float*)d_in[4];

    char* ws = (char*)d_ws;
    size_t off = 0;
    auto alloc = [&](size_t bytes) -> void* {
        void* p = ws + off;
        off += (bytes + 255) & ~(size_t)255;
        return p;
    };
    float* scores              = (float*)alloc((size_t)NB * NPRED * 4);
    float* sel_score           = (float*)alloc((size_t)NB * NSEL * 4);
    int* sel_idx               = (int*)alloc((size_t)NB * NSEL * 4);
    float* sel_box             = (float*)alloc((size_t)NB * NSEL * 16);
    float* sel_cls             = (float*)alloc((size_t)NB * NSEL * 4);
    unsigned long long* maskT  = (unsigned long long*)alloc((size_t)NB * 16 * NSEL * 8);
    float* out = (float*)d_out;

    k_score<<<(NB * NPRED + 255) / 256, 256, 0, stream>>>(r0, r1, r2, scores);
    k_topk<<<NB, 1024, 0, stream>>>(scores, sel_score, sel_idx);
    k_decode<<<(NB * NSEL + 255) / 256, 256, 0, stream>>>(r0, r1, r2, strd, ag,
                                                          sel_score, sel_idx, sel_box, sel_cls);
    k_mask<<<NB * 64, 256, 0, stream>>>(sel_box, maskT);
    k_sweepout<<<NB, 1024, 0, stream>>>(sel_score, sel_box, sel_cls, maskT, out);
}

// Round 5
// 307.565 us; speedup vs baseline: 1.0623x; 1.0623x over previous
//
#include <hip/hip_runtime.h>

#define NB 64
#define NPRED 25200
#define NCAND 2048
#define NSEL 1024
#define NDET 300
#define NBINS 8192
#define CONF_T 0.25f
#define IOU_T 0.45f
#define BASE_BITS 0x3E800000u   // bits of 0.25f

__device__ __forceinline__ float sigmoidf_(float x) {
    return 1.0f / (1.0f + expf(-x));
}

// ---------------------------------------------------------------- scores
// score = valid ? obj*sigmoid(max raw_cls) : 0   (monotonicity of sigmoid)
__global__ void k_score(const float* __restrict__ r0,
                        const float* __restrict__ r1,
                        const float* __restrict__ r2,
                        float* __restrict__ scores) {
    int tid = blockIdx.x * blockDim.x + threadIdx.x;
    if (tid >= NB * NPRED) return;
    int img = tid / NPRED;
    int n = tid - img * NPRED;
    const float* src;
    int local, cells;
    if (n < 19200)      { src = r0; local = n;         cells = 6400; }
    else if (n < 24000) { src = r1; local = n - 19200; cells = 1600; }
    else                { src = r2; local = n - 24000; cells = 400;  }
    long base = ((long)img * 3 * cells + local) * 20;
    const float4* p = (const float4*)(src + base + 4);   // raw[4..19], 16B aligned
    float4 v0 = p[0], v1 = p[1], v2 = p[2], v3 = p[3];
    float obj = sigmoidf_(v0.x);
    float m = v0.y;
    m = fmaxf(m, v0.z); m = fmaxf(m, v0.w);
    m = fmaxf(m, v1.x); m = fmaxf(m, v1.y); m = fmaxf(m, v1.z); m = fmaxf(m, v1.w);
    m = fmaxf(m, v2.x); m = fmaxf(m, v2.y); m = fmaxf(m, v2.z); m = fmaxf(m, v2.w);
    m = fmaxf(m, v3.x); m = fmaxf(m, v3.y); m = fmaxf(m, v3.z); m = fmaxf(m, v3.w);
    float best = obj * sigmoidf_(m);
    float sc = (obj > CONF_T && best > CONF_T) ? best : 0.0f;
    scores[tid] = sc;
}

// ---------------------------------------------------------------- top-k (fused select+sort)
__global__ __launch_bounds__(1024) void k_topk(const float* __restrict__ scores,
                                               float* __restrict__ sel_score,
                                               int* __restrict__ sel_idx) {
    __shared__ unsigned int hist[NBINS];
    __shared__ unsigned int bufA[1024];
    __shared__ unsigned int bufB[1024];
    __shared__ unsigned long long sbuf[NCAND];
    __shared__ unsigned int s_thr;
    __shared__ unsigned int s_cnt;
    int img = blockIdx.x;
    int t = threadIdx.x;
    for (int b = t; b < NBINS; b += 1024) hist[b] = 0;
    if (t == 0) { s_thr = 0; s_cnt = 0; }
    __syncthreads();
    const float* sc = scores + (long)img * NPRED;
    float v[25];
#pragma unroll
    for (int i = 0; i < 25; ++i) {
        int n = t + i * 1024;
        v[i] = (n < NPRED) ? sc[n] : 0.0f;
        if (v[i] > CONF_T) {
            unsigned bin = (__float_as_uint(v[i]) - BASE_BITS) >> 11;
            if (bin > NBINS - 1u) bin = NBINS - 1u;
            atomicAdd(&hist[bin], 1u);
        }
    }
    __syncthreads();
    unsigned h[8];
    unsigned cs = 0;
    for (int b = 0; b < 8; ++b) { h[b] = hist[t * 8 + b]; cs += h[b]; }
    bufA[t] = cs;
    __syncthreads();
    unsigned int* srcp = bufA;
    unsigned int* dstp = bufB;
    for (int ofs = 1; ofs < 1024; ofs <<= 1) {
        unsigned vv = srcp[t];
        if (t >= ofs) vv += srcp[t - ofs];
        dstp[t] = vv;
        __syncthreads();
        unsigned int* tmp = srcp; srcp = dstp; dstp = tmp;
    }
    unsigned total = srcp[1023];
    unsigned above = total - srcp[t];
    if (total >= NSEL) {
        unsigned c = above;
        for (int b = 7; b >= 0; --b) {
            unsigned ci = c + h[b];
            if (c < NSEL && ci >= NSEL) {
                s_thr = BASE_BITS + ((unsigned)(t * 8 + b) << 11);
            }
            c = ci;
        }
    }
    __syncthreads();
    unsigned thr = s_thr;
#pragma unroll
    for (int i = 0; i < 25; ++i) {
        int n = t + i * 1024;
        if (v[i] > CONF_T) {
            unsigned bits = __float_as_uint(v[i]);
            if (bits >= thr) {
                unsigned pos = atomicAdd(&s_cnt, 1u);
                if (pos < NCAND)
                    sbuf[pos] = ((unsigned long long)bits << 32) |
                                (unsigned long long)(0xFFFFFFFFu - (unsigned)n);
            }
        }
    }
    __syncthreads();
    for (unsigned pos = s_cnt + (unsigned)t; pos < NCAND; pos += 1024) sbuf[pos] = 0ull;
    __syncthreads();
    for (int k = 2; k <= NCAND; k <<= 1) {
        for (int j = k >> 1; j > 0; j >>= 1) {
            for (int e = t; e < NCAND; e += 1024) {
                int p = e ^ j;
                if (p > e) {
                    unsigned long long a = sbuf[e], b = sbuf[p];
                    bool up = ((e & k) == 0);
                    if ((a < b) == up) { sbuf[e] = b; sbuf[p] = a; }
                }
            }
            __syncthreads();
        }
    }
    unsigned long long key = sbuf[t];
    float scv = __uint_as_float((unsigned)(key >> 32));
    int idx = (int)(0xFFFFFFFFu - (unsigned)(key & 0xFFFFFFFFull));
    sel_score[img * NSEL + t] = scv;
    sel_idx[img * NSEL + t] = idx;
}

// ---------------------------------------------------------------- decode selected
__global__ void k_decode(const float* __restrict__ r0, const float* __restrict__ r1,
                         const float* __restrict__ r2, const float* __restrict__ strd,
                         const float* __restrict__ ag,
                         const float* __restrict__ sel_score,
                         const int* __restrict__ sel_idx,
                         float* __restrict__ sel_box, float* __restrict__ sel_cls) {
    int t = blockIdx.x * blockDim.x + threadIdx.x;
    if (t >= NB * NSEL) return;
    int img = t >> 10;
    float scv = sel_score[t];
    float4 bb = make_float4(0.f, 0.f, 0.f, 0.f);
    float cls = 0.0f;
    if (scv > CONF_T) {
        int n = sel_idx[t];
        const float* src;
        int a, y, x, cells, sidx, nxl;
        if (n < 19200) {
            sidx = 0; src = r0; cells = 6400; nxl = 80;
            int l = n;            a = l / 6400; int r = l - a * 6400; y = r / 80; x = r - y * 80;
        } else if (n < 24000) {
            sidx = 1; src = r1; cells = 1600; nxl = 40;
            int l = n - 19200;    a = l / 1600; int r = l - a * 1600; y = r / 40; x = r - y * 40;
        } else {
            sidx = 2; src = r2; cells = 400; nxl = 20;
            int l = n - 24000;    a = l / 400;  int r = l - a * 400;  y = r / 20; x = r - y * 20;
        }
        long base = (((long)img * 3 + a) * cells + (long)y * nxl + x) * 20;
        const float4* p = (const float4*)(src + base);
        float4 v0 = p[0];
        float st = strd[sidx];
        float aw = ag[(sidx * 3 + a) * 2 + 0];
        float ah = ag[(sidx * 3 + a) * 2 + 1];
        float cx = (sigmoidf_(v0.x) * 2.0f - 0.5f + (float)x) * st;
        float cy = (sigmoidf_(v0.y) * 2.0f - 0.5f + (float)y) * st;
        float tw = sigmoidf_(v0.z) * 2.0f;
        float th = sigmoidf_(v0.w) * 2.0f;
        float w = tw * tw * aw;
        float h = th * th * ah;
        bb.x = cx - w * 0.5f;
        bb.y = cy - h * 0.5f;
        bb.z = cx + w * 0.5f;
        bb.w = cy + h * 0.5f;
        float4 c0 = p[1], c1 = p[2], c2 = p[3], c3 = p[4];
        float vals[15] = { c0.y, c0.z, c0.w,
                           c1.x, c1.y, c1.z, c1.w,
                           c2.x, c2.y, c2.z, c2.w,
                           c3.x, c3.y, c3.z, c3.w };
        float bv = vals[0]; int bi = 0;
        for (int k = 1; k < 15; ++k) if (vals[k] > bv) { bv = vals[k]; bi = k; }
        cls = (float)bi;
    }
    ((float4*)sel_box)[t] = bb;
    sel_cls[t] = cls;
}

// ---------------------------------------------------------------- IoU mask (tiled)
// maskT[img][jt][i]: bit b set <=> j=jt*64+b > i and IoU > 0.45.
__global__ __launch_bounds__(256) void k_mask(const float* __restrict__ sel_box,
                                              unsigned long long* __restrict__ maskT) {
    __shared__ float4 boxi[64];
    __shared__ float areai[64];
    int img = blockIdx.x >> 6;
    int rem = blockIdx.x & 63;
    int it = rem >> 2;          // 0..15
    int q  = rem & 3;           // 0..3
    int t = threadIdx.x;
    int wv = t >> 6;            // wave 0..3
    int lane = t & 63;
    const float4* bsrc = (const float4*)sel_box + (long)img * NSEL;
    if (t < 64) {
        float4 b = bsrc[it * 64 + t];
        boxi[t] = b;
        areai[t] = (b.z - b.x) * (b.w - b.y);
    }
    __syncthreads();
    int jt = q * 4 + wv;        // 0..15
    unsigned long long* dst =
        maskT + ((long)img * 16 + jt) * NSEL + it * 64 + lane;
    if (jt < it) { *dst = 0ull; return; }
    float4 bj = bsrc[jt * 64 + lane];
    float aj = (bj.z - bj.x) * (bj.w - bj.y);
    bool diag = (jt == it);
    unsigned long long myword = 0;
    for (int i = 0; i < 64; ++i) {
        float4 bi = boxi[i];
        float ai = areai[i];
        float iw = fminf(bi.z, bj.z) - fmaxf(bi.x, bj.x);
        float ih = fminf(bi.w, bj.w) - fmaxf(bi.y, bj.y);
        iw = fmaxf(iw, 0.0f);
        ih = fmaxf(ih, 0.0f);
        float inter = iw * ih;
        float iou = inter / (ai + aj - inter + 1e-7f);
        bool pred = (iou > IOU_T) && (!diag || lane > i);
        unsigned long long bal = __ballot(pred);
        if (lane == i) myword = bal;
    }
    *dst = myword;
}

// ---------------------------------------------------------------- sweep + output (blocked resolve)
// Wave w owns keep word w. Preloads its mask column m[t]=maskT[img][w][t*64+lane]
// (coalesced, issued upfront). 16 sequential steps: at step t, wave t resolves
// its 64 rows in-register (readlane operands loop-invariant -> chain is pure
// scalar select/and, ~4-8 cyc/row), publishes to LDS; waves w>t apply the kept
// set in parallel via shuffle-OR reduce. Bit-identical to the reference
// fori_loop semantics.
__global__ __launch_bounds__(1024) void k_sweepout(const float* __restrict__ sel_score,
                                                   const float* __restrict__ sel_box,
                                                   const float* __restrict__ sel_cls,
                                                   const unsigned long long* __restrict__ maskT,
                                                   float* __restrict__ out) {
    __shared__ unsigned long long keepL[16];
    __shared__ unsigned int wsum[16];
    int img = blockIdx.x, t = threadIdx.x;
    int lane = t & 63, wid = t >> 6;
    const float* sc = sel_score + img * NSEL;

    // preload this wave's mask column (tiles above the diagonal are zero)
    unsigned long long m[16];
    const unsigned long long* col = maskT + ((long)img * 16 + wid) * NSEL + lane;
#pragma unroll
    for (int tt = 0; tt < 16; ++tt)
        m[tt] = (tt <= wid) ? col[tt * 64] : 0ull;

    // zero the output while loads are in flight
    float* o = out + (long)img * NDET * 6;
    for (int e = t; e < NDET * 6; e += 1024) o[e] = 0.0f;

    unsigned long long kw = __ballot(sc[wid * 64 + lane] > CONF_T);

    for (int tt = 0; tt < 16; ++tt) {
        if (wid == tt) {
            unsigned mlo = (unsigned)(m[tt] & 0xFFFFFFFFull);
            unsigned mhi = (unsigned)(m[tt] >> 32);
#pragma unroll
            for (int i = 0; i < 64; ++i) {
                unsigned rlo = (unsigned)__builtin_amdgcn_readlane((int)mlo, i);
                unsigned rhi = (unsigned)__builtin_amdgcn_readlane((int)mhi, i);
                unsigned long long mrow =
                    ((unsigned long long)rhi << 32) | (unsigned long long)rlo;
                kw = ((kw >> i) & 1ull) ? (kw & ~mrow) : kw;
            }
            if (lane == 0) keepL[tt] = kw;
        }
        __syncthreads();
        if (wid > tt) {
            unsigned long long kwt = keepL[tt];
            unsigned long long v = ((kwt >> lane) & 1ull) ? m[tt] : 0ull;
#pragma unroll
            for (int s = 1; s < 64; s <<= 1)
                v |= __shfl_xor(v, s, 64);
            kw &= ~v;
        }
    }

    // output: rank kept rows, emit first 300
    bool kept = (kw >> lane) & 1ull;
    unsigned long long bal = __ballot(kept);
    int lrank = __popcll(bal & ((1ull << lane) - 1ull));
    if (lane == 0) wsum[wid] = (unsigned)__popcll(bal);
    __syncthreads();
    int off = 0;
    for (int ww = 0; ww < wid; ++ww) off += (int)wsum[ww];
    int rank = off + lrank;
    if (kept && rank < NDET) {
        float4 b = ((const float4*)sel_box)[img * NSEL + t];
        float s = sc[t];
        float c = sel_cls[img * NSEL + t];
        float* row = o + rank * 6;
        row[0] = b.x; row[1] = b.y; row[2] = b.z; row[3] = b.w;
        row[4] = s;   row[5] = c;
    }
}

// ---------------------------------------------------------------- launch
extern "C" void kernel_launch(void* const* d_in, const int* in_sizes, int n_in,
                              void* d_out, int out_size, void* d_ws, size_t ws_size,
                              hipStream_t stream) {
    const float* r0   = (const float*)d_in[0];
    const float* r1   = (const float*)d_in[1];
    const float* r2   = (const float*)d_in[2];
    const float* strd = (const float*)d_in[3];
    const float* ag   = (const float*)d_in[4];

    char* ws = (char*)d_ws;
    size_t off = 0;
    auto alloc = [&](size_t bytes) -> void* {
        void* p = ws + off;
        off += (bytes + 255) & ~(size_t)255;
        return p;
    };
    float* scores              = (float*)alloc((size_t)NB * NPRED * 4);
    float* sel_score           = (float*)alloc((size_t)NB * NSEL * 4);
    int* sel_idx               = (int*)alloc((size_t)NB * NSEL * 4);
    float* sel_box             = (float*)alloc((size_t)NB * NSEL * 16);
    float* sel_cls             = (float*)alloc((size_t)NB * NSEL * 4);
    unsigned long long* maskT  = (unsigned long long*)alloc((size_t)NB * 16 * NSEL * 8);
    float* out = (float*)d_out;

    k_score<<<(NB * NPRED + 255) / 256, 256, 0, stream>>>(r0, r1, r2, scores);
    k_topk<<<NB, 1024, 0, stream>>>(scores, sel_score, sel_idx);
    k_decode<<<(NB * NSEL + 255) / 256, 256, 0, stream>>>(r0, r1, r2, strd, ag,
                                                          sel_score, sel_idx, sel_box, sel_cls);
    k_mask<<<NB * 64, 256, 0, stream>>>(sel_box, maskT);
    k_sweepout<<<NB, 1024, 0, stream>>>(sel_score, sel_box, sel_cls, maskT, out);
}